// Round 2
// baseline (19141.547 us; speedup 1.0000x reference)
//
#include <hip/hip_runtime.h>
#include <math.h>

// Problem constants
#define NB 64
#define NL 2048
#define NH 256
#define OUT_ELEMS 33554432   // NB*NL*NH
#define HSZ 16384            // NB*NH

// Agent-scope write-through store: lands at MALL (coherence point), never
// dirty in L1/L2 -> cross-XCD consumers can't lose it to buffer_inv, and the
// release flag's vmcnt(0) suffices for visibility ordering.
__device__ __forceinline__ void st_agent(float* p, float v) {
    __hip_atomic_store(p, v, __ATOMIC_RELAXED, __HIP_MEMORY_SCOPE_AGENT);
}

// ---------------------------------------------------------------------------
// init: zero sync flags, preload h_0 into the "previous" (parity-1) h buffers
// ws layout: flags = (unsigned*)d_ws [128 ints]
//            wsf   = (float*)(d_ws+1024):
//              Hb0[2][HSZ] | Hb1[2][HSZ] | Pb[2][HSZ]
// ---------------------------------------------------------------------------
__global__ void k_init(const float* __restrict__ h0, float* __restrict__ wsf,
                       unsigned* __restrict__ flags)
{
    int tid = blockIdx.x * 256 + threadIdx.x;
    if (tid < 128) flags[tid] = 0u;
    if (tid < HSZ) {
        wsf[HSZ + tid]           = h0[tid];         // Hb0[1] = h_0 layer0
        wsf[2 * HSZ + HSZ + tid] = h0[HSZ + tid];   // Hb1[1] = h_0 layer1
    }
}

// ---------------------------------------------------------------------------
// Phase A: pre0[b][t][n] = x[b][t][:] @ WI0 + BI0   (written into d_out)
// M=131072 (b*2048+t), N=256, K=256. BM=128, BN=64, BK=16, 256 threads.
// ---------------------------------------------------------------------------
__global__ __launch_bounds__(256) void k_gemm_pre0(
    const float* __restrict__ x, const float* __restrict__ WI,
    const float* __restrict__ BI, float* __restrict__ pre)
{
    __shared__ float As[16][132];   // A stored transposed [k][m], padded
    __shared__ float Bs[16][68];
    const int tid = threadIdx.x;
    const size_t mbase = (size_t)blockIdx.x * 128;
    const int nbase = blockIdx.y * 64;
    const int am = tid >> 1, ak = (tid & 1) * 8;
    const int bk = tid >> 4, bn = (tid & 15) * 4;
    const int ty = tid >> 4, tx = tid & 15;
    const int m0 = ty * 8, n0 = tx * 4;
    float acc[8][4];
    #pragma unroll
    for (int i = 0; i < 8; i++)
        #pragma unroll
        for (int j = 0; j < 4; j++) acc[i][j] = 0.f;

    for (int k0 = 0; k0 < 256; k0 += 16) {
        float4 a0 = *(const float4*)(x + (mbase + am) * 256 + k0 + ak);
        float4 a1 = *(const float4*)(x + (mbase + am) * 256 + k0 + ak + 4);
        float4 bv = *(const float4*)(WI + (size_t)(k0 + bk) * 256 + nbase + bn);
        __syncthreads();
        As[ak + 0][am] = a0.x; As[ak + 1][am] = a0.y;
        As[ak + 2][am] = a0.z; As[ak + 3][am] = a0.w;
        As[ak + 4][am] = a1.x; As[ak + 5][am] = a1.y;
        As[ak + 6][am] = a1.z; As[ak + 7][am] = a1.w;
        *(float4*)&Bs[bk][bn] = bv;
        __syncthreads();
        #pragma unroll
        for (int kk = 0; kk < 16; kk++) {
            float4 av0 = *(const float4*)&As[kk][m0];
            float4 av1 = *(const float4*)&As[kk][m0 + 4];
            float4 bv4 = *(const float4*)&Bs[kk][n0];
            float a[8] = {av0.x, av0.y, av0.z, av0.w, av1.x, av1.y, av1.z, av1.w};
            float b[4] = {bv4.x, bv4.y, bv4.z, bv4.w};
            #pragma unroll
            for (int i = 0; i < 8; i++)
                #pragma unroll
                for (int j = 0; j < 4; j++)
                    acc[i][j] += a[i] * b[j];
        }
    }
    float4 bi = *(const float4*)(BI + nbase + n0);
    #pragma unroll
    for (int i = 0; i < 8; i++) {
        float4 r;
        r.x = acc[i][0] + bi.x; r.y = acc[i][1] + bi.y;
        r.z = acc[i][2] + bi.z; r.w = acc[i][3] + bi.w;
        *(float4*)(pre + (mbase + m0 + i) * 256 + nbase + n0) = r;
    }
}

// ---------------------------------------------------------------------------
// Persistent recurrence. 96 wgs x 512 threads, all co-resident.
//   role 0 (wg  0..31): h0_t = tanh(pre0 + h0_{t-1}@WH0 + BH0)     -> Hb0
//   role 1 (wg 32..63): P_t  = h0_t@WI1 + BI1                      -> Pb
//   role 2 (wg 64..95): h1_t = tanh(P_t + h1_{t-1}@WH1 + BH1)      -> Hb1, out
// Each wg owns 8 output columns j0..j0+7. Per lane: j = j0+(kc&7),
// k-half = kc>>3 (128 k's), weights W[128] persistent in VGPRs,
// 2 batch rows per lane (otile), one shfl_xor(8) combines k-halves.
// flag[w] = n  <=>  wg w finished steps 0..n-1  (agent-scope release)
// All published data goes through st_agent (write-through dwords).
// ---------------------------------------------------------------------------
__device__ __forceinline__ void spin_acquire(unsigned* fa, int ta,
                                             unsigned* fb, int tb, int lane)
{
    for (;;) {
        int va = 0x7fffffff, vb = 0x7fffffff;
        if (lane < 32) {
            va = (int)__hip_atomic_load(&fa[lane], __ATOMIC_RELAXED,
                                        __HIP_MEMORY_SCOPE_AGENT);
            vb = (int)__hip_atomic_load(&fb[lane], __ATOMIC_RELAXED,
                                        __HIP_MEMORY_SCOPE_AGENT);
        }
        if (__all((va >= ta) && (vb >= tb))) break;
        __builtin_amdgcn_s_sleep(1);
    }
    __builtin_amdgcn_fence(__ATOMIC_ACQUIRE, "agent");  // invalidate stale L1/L2
}

__global__ __launch_bounds__(512, 2) void k_rnn_persist(
    const float* __restrict__ WI, const float* __restrict__ BI,
    const float* __restrict__ WH, const float* __restrict__ BH,
    float* out, float* wsf, unsigned* flags)
{
    const int wg   = blockIdx.x;      // 0..95
    const int role = wg >> 5;         // 0,1,2
    const int w    = wg & 31;
    const int j0   = w * 8;
    const int tid  = threadIdx.x;
    const int lane = tid & 63;
    const int wave = tid >> 6;
    const int otile = wave * 4 + (lane >> 4);   // 0..31
    const int b0    = otile * 2;                // 2 batch rows per lane
    const int kc    = lane & 15;
    const int khalf = kc >> 3;                  // 0/1: which 128 k's
    const int jcol  = j0 + (kc & 7);

    float* Hb0 = wsf;
    float* Hb1 = wsf + 2 * HSZ;
    float* Pb  = wsf + 4 * HSZ;
    unsigned* flag0 = flags;
    unsigned* flagA = flags + 32;
    unsigned* flag1 = flags + 64;

    // --- persistent weights in VGPRs: W[kk] = Wsrc[khalf*128+kk][jcol] ---
    const float* wsrc = (role == 0) ? WH
                      : (role == 1) ? (WI + 65536)
                                    : (WH + 65536);
    float W[128];
    {
        const float* ws2 = wsrc + (size_t)(khalf * 128) * 256 + jcol;
        #pragma unroll
        for (int kk = 0; kk < 128; kk++) W[kk] = ws2[(size_t)kk * 256];
    }
    const bool writer = (khalf == 0);
    float bias = 0.f;
    if (writer) {
        if (role == 0)      bias = BH[jcol];
        else if (role == 1) bias = BI[256 + jcol];
        else                bias = BH[256 + jcol];
    }

    // wait-condition setup: need all fa >= t+da and all fb >= t+db
    unsigned *wfa, *wfb; int da, db;
    if (role == 0)      { wfa = flag0; da = 0;  wfb = flagA; db = -1; }
    else if (role == 1) { wfa = flag0; da = 1;  wfb = flag1; db = -1; }
    else                { wfa = flagA; da = 1;  wfb = flag1; db = 0;  }
    unsigned* myflag = (role == 0) ? &flag0[w] : (role == 1) ? &flagA[w] : &flag1[w];

    float* hbase = (role == 2) ? Hb1 : Hb0;
    const int hoff = (role == 1) ? 0 : 1;   // role1 reads parity t, others t-1

    for (int t = 0; t < NL; t++) {
        const int par = t & 1;
        // prefetch pre-activation (written by phase A; safe: role 2 overwrites
        // out[t] only after role 0 finished step t)
        float p0 = 0.f, p1 = 0.f;
        if (role == 0 && writer) {
            p0 = out[(size_t)b0 * (NL * NH) + (size_t)t * NH + jcol];
            p1 = out[(size_t)(b0 + 1) * (NL * NH) + (size_t)t * NH + jcol];
        }
        if (wave == 0) spin_acquire(wfa, t + da, wfb, t + db, lane);
        __syncthreads();

        const float* hsrc = hbase + ((t + hoff) & 1) * HSZ;
        float q0 = 0.f, q1 = 0.f;
        if (role == 2 && writer) {   // partial from L1A (ready: flagA >= t+1)
            q0 = Pb[par * HSZ + b0 * 256 + jcol];
            q1 = Pb[par * HSZ + (b0 + 1) * 256 + jcol];
        }
        const float* hp0 = hsrc + b0 * 256 + khalf * 128;
        const float* hp1 = hp0 + 256;
        float s00 = 0, s01 = 0, s02 = 0, s03 = 0;
        float s10 = 0, s11 = 0, s12 = 0, s13 = 0;
        #pragma unroll
        for (int q = 0; q < 32; q++) {
            float4 a = *(const float4*)(hp0 + 4 * q);
            float4 b = *(const float4*)(hp1 + 4 * q);
            s00 += a.x * W[4 * q];     s01 += a.y * W[4 * q + 1];
            s02 += a.z * W[4 * q + 2]; s03 += a.w * W[4 * q + 3];
            s10 += b.x * W[4 * q];     s11 += b.y * W[4 * q + 1];
            s12 += b.z * W[4 * q + 2]; s13 += b.w * W[4 * q + 3];
        }
        float acc0 = (s00 + s01) + (s02 + s03);
        float acc1 = (s10 + s11) + (s12 + s13);
        acc0 += __shfl_xor(acc0, 8, 64);   // combine the two k-halves
        acc1 += __shfl_xor(acc1, 8, 64);

        if (writer) {
            if (role == 0) {
                float v0 = tanhf(acc0 + p0 + bias);
                float v1 = tanhf(acc1 + p1 + bias);
                st_agent(&Hb0[par * HSZ + b0 * 256 + jcol], v0);
                st_agent(&Hb0[par * HSZ + (b0 + 1) * 256 + jcol], v1);
                if (t == NL - 1) {
                    st_agent(&out[OUT_ELEMS + b0 * 256 + jcol], v0);
                    st_agent(&out[OUT_ELEMS + (b0 + 1) * 256 + jcol], v1);
                }
            } else if (role == 1) {
                st_agent(&Pb[par * HSZ + b0 * 256 + jcol], acc0 + bias);
                st_agent(&Pb[par * HSZ + (b0 + 1) * 256 + jcol], acc1 + bias);
            } else {
                float v0 = tanhf(acc0 + q0 + bias);
                float v1 = tanhf(acc1 + q1 + bias);
                st_agent(&Hb1[par * HSZ + b0 * 256 + jcol], v0);
                st_agent(&Hb1[par * HSZ + (b0 + 1) * 256 + jcol], v1);
                st_agent(&out[(size_t)b0 * (NL * NH) + (size_t)t * NH + jcol], v0);
                st_agent(&out[(size_t)(b0 + 1) * (NL * NH) + (size_t)t * NH + jcol], v1);
                if (t == NL - 1) {
                    st_agent(&out[OUT_ELEMS + HSZ + b0 * 256 + jcol], v0);
                    st_agent(&out[OUT_ELEMS + HSZ + (b0 + 1) * 256 + jcol], v1);
                }
            }
        }
        __syncthreads();   // all waves' write-through stores issued+drained
        if (tid == 0)
            __hip_atomic_store(myflag, (unsigned)(t + 1), __ATOMIC_RELEASE,
                               __HIP_MEMORY_SCOPE_AGENT);
    }
}

// ---------------------------------------------------------------------------
extern "C" void kernel_launch(void* const* d_in, const int* in_sizes, int n_in,
                              void* d_out, int out_size, void* d_ws, size_t ws_size,
                              hipStream_t stream)
{
    const float* x  = (const float*)d_in[0];
    const float* h0 = (const float*)d_in[1];
    const float* WI = (const float*)d_in[2];
    const float* BI = (const float*)d_in[3];
    const float* WH = (const float*)d_in[4];
    const float* BH = (const float*)d_in[5];
    float* out = (float*)d_out;
    unsigned* flags = (unsigned*)d_ws;
    float* wsf = (float*)((char*)d_ws + 1024);   // needs ~385 KB of d_ws

    k_init<<<64, 256, 0, stream>>>(h0, wsf, flags);
    k_gemm_pre0<<<dim3(1024, 4), 256, 0, stream>>>(x, WI, BI, out);
    k_rnn_persist<<<96, 512, 0, stream>>>(WI, BI, WH, BH, out, wsf, flags);
}